// Round 7
// baseline (290.721 us; speedup 1.0000x reference)
//
#include <hip/hip_runtime.h>
#include <hip/hip_bf16.h>
#include <stdint.h>

// ---------------------------------------------------------------------------
// SelfAttention: B=4 S=2048 D=1024 H=16 HD=64. I/O dtype: FLOAT32.
//   0) cvt: x, Wq, Wk, Wv, Wo  f32 -> bf16
//   1) gemm_qkv R15: R12 body/tiling (BK=64, 128x128, grid (24,64) 2D — the
//      80.5us verified config; R14's XCD swizzle hurt, reverted) converted
//      to DOUBLE-BUFFERED BK=64 (attn's verified loop shape): one barrier
//      per K-step, stage(next) issued before compute(cur). LDS 64KB.
//      R13 lesson kept: phases stay fat (32 MFMA); iteration count stays 16.
//   2) attn R12 (unchanged, 79.5us): LDS dbuf ASYNC staging + ones-MFMA
//      denominator + XCD-locality swizzle (FETCH 140->25MB verified).
//   3) gemm_o R15: same dbuf transform, grid (8,64) 2D.
// ---------------------------------------------------------------------------

typedef __bf16 bf16;
typedef __bf16 bf16x8 __attribute__((ext_vector_type(8)));
typedef __bf16 bf16x4 __attribute__((ext_vector_type(4)));
typedef float  f32x4  __attribute__((ext_vector_type(4)));

#define MFMA_BF16(A, B, C) __builtin_amdgcn_mfma_f32_16x16x32_bf16(A, B, C, 0, 0, 0)
#define EXP2F(x) __builtin_amdgcn_exp2f(x)

#define ASYNC_CP16(DST_LDS, SRC_G)                                            \
  __builtin_amdgcn_global_load_lds(                                           \
      (__attribute__((address_space(1))) void*)(SRC_G),                       \
      (__attribute__((address_space(3))) void*)(DST_LDS), 16, 0, 0)

// ---------------------------------------------------------------------------
__global__ __launch_bounds__(256) void cvt5(
    const float* __restrict__ s0, bf16* __restrict__ d0, int n0,
    const float* __restrict__ s1, bf16* __restrict__ d1, int n1,
    const float* __restrict__ s2, bf16* __restrict__ d2, int n2,
    const float* __restrict__ s3, bf16* __restrict__ d3, int n3,
    const float* __restrict__ s4, bf16* __restrict__ d4, int n4)
{
  const float* s; bf16* d; int n;
  switch (blockIdx.y) {
    case 0: s = s0; d = d0; n = n0; break;
    case 1: s = s1; d = d1; n = n1; break;
    case 2: s = s2; d = d2; n = n2; break;
    case 3: s = s3; d = d3; n = n3; break;
    default: s = s4; d = d4; n = n4; break;
  }
  const int stride = gridDim.x * blockDim.x * 4;
  for (int i = (blockIdx.x * blockDim.x + threadIdx.x) * 4; i < n; i += stride) {
    const float4 v = *(const float4*)(s + i);
    bf16x4 o;
    o[0] = (bf16)v.x; o[1] = (bf16)v.y; o[2] = (bf16)v.z; o[3] = (bf16)v.w;
    *(bf16x4*)(d + i) = o;
  }
}

// ---------------------------------------------------------------------------
// Fused QKV GEMM. grid (24,64): blockIdx.x>>3 selects {Q,K,V}; &7 is nbase.
// V stored chunk-major: Vt[bh][s>>6][hd][s&63].
// R15: BK=64 double-buffer, one barrier/iter (attn loop shape).
// ---------------------------------------------------------------------------
__global__ __launch_bounds__(256, 4) void gemm_qkv(
    const bf16* __restrict__ X,
    const bf16* __restrict__ Wq, const bf16* __restrict__ Wk,
    const bf16* __restrict__ Wv,
    const float* __restrict__ bq, const float* __restrict__ bk,
    const float* __restrict__ bv,
    bf16* __restrict__ Qo, bf16* __restrict__ Ko, bf16* __restrict__ Vo,
    float qscale)
{
  constexpr int N = 1024, K = 1024;
  __shared__ alignas(16) bf16 As[2][8192];
  __shared__ alignas(16) bf16 Bs[2][8192];

  const int sel = blockIdx.x >> 3;          // 0=Q 1=K 2=V
  const bf16*  W    = (sel == 0) ? Wq : (sel == 1) ? Wk : Wv;
  const float* bias = (sel == 0) ? bq : (sel == 1) ? bk : bv;
  bf16*        Y    = (sel == 0) ? Qo : (sel == 1) ? Ko : Vo;
  const float scale = (sel == 0) ? qscale : 1.0f;

  const int tid  = threadIdx.x;
  const int lane = tid & 63;
  const int wv   = tid >> 6;
  const int l15  = lane & 15;
  const int quad = lane >> 4;
  const int wm   = (wv >> 1) * 64;
  const int wn   = (wv & 1) * 64;
  const int nbase = (blockIdx.x & 7) * 128;
  const int mbase = blockIdx.y * 128;

  f32x4 acc[4][4];
  #pragma unroll
  for (int i = 0; i < 4; ++i)
    #pragma unroll
    for (int j = 0; j < 4; ++j)
      acc[i][j] = (f32x4){0.f, 0.f, 0.f, 0.f};

  const int r8 = lane >> 3;
  const int oc = (lane & 7) ^ r8;
  const size_t lrowA = (size_t)(mbase + wv * 32 + r8);
  const size_t lrowB = (size_t)(nbase + wv * 32 + r8);

#define GSTAGE(BUF, KB)                                                       \
  {                                                                           \
    _Pragma("unroll")                                                         \
    for (int c = 0; c < 4; ++c) {                                             \
      ASYNC_CP16(&As[BUF][(wv * 32 + c * 8) * 64],                            \
                 X + (lrowA + c * 8) * K + (KB) + oc * 8);                    \
      ASYNC_CP16(&Bs[BUF][(wv * 32 + c * 8) * 64],                            \
                 W + (lrowB + c * 8) * K + (KB) + oc * 8);                    \
    }                                                                         \
  }

  GSTAGE(0, 0);
  int cur = 0;
  for (int kb = 0; kb < K; kb += 64) {
    __syncthreads();                       // drains stage(cur); readers of cur^1 done
    if (kb + 64 < K) GSTAGE(cur ^ 1, kb + 64);
    #pragma unroll
    for (int ks = 0; ks < 2; ++ks) {
      bf16x8 af[4], bfr[4];
      #pragma unroll
      for (int t = 0; t < 4; ++t) {
        const int ma = wm + t * 16 + l15;
        af[t]  = *(const bf16x8*)(&As[cur][(ma * 8 + ((ks * 4 + quad) ^ (ma & 7))) * 8]);
        const int nb = wn + t * 16 + l15;
        bfr[t] = *(const bf16x8*)(&Bs[cur][(nb * 8 + ((ks * 4 + quad) ^ (nb & 7))) * 8]);
      }
      #pragma unroll
      for (int i = 0; i < 4; ++i)
        #pragma unroll
        for (int j = 0; j < 4; ++j)
          acc[i][j] = MFMA_BF16(af[i], bfr[j], acc[i][j]);
    }
    cur ^= 1;
  }
#undef GSTAGE

  #pragma unroll
  for (int i = 0; i < 4; ++i) {
    const int row0 = mbase + wm + i * 16 + quad * 4;
    #pragma unroll
    for (int j = 0; j < 4; ++j) {
      const int col = nbase + wn + j * 16 + l15;
      const float bv2 = bias[col];
      #pragma unroll
      for (int r = 0; r < 4; ++r) {
        const float v = (acc[i][j][r] + bv2) * scale;
        const int row = row0 + r;
        if (sel != 2) {
          Y[(size_t)row * N + col] = (bf16)v;
        } else {
          const int bb = row >> 11, s  = row & 2047;
          const int hh = col >> 6,  hd = col & 63;
          // chunk-major: [bh][s>>6][hd][s&63]
          Y[(size_t)(bb * 16 + hh) * (2048 * 64) + (size_t)(s >> 6) * 4096 +
            hd * 64 + (s & 63)] = (bf16)v;
        }
      }
    }
  }
}

// ---------------------------------------------------------------------------
// O-projection GEMM (f32 out), 128x128 tile, grid (8,64).
// R15: BK=64 double-buffer, one barrier/iter.
// ---------------------------------------------------------------------------
__global__ __launch_bounds__(256) void gemm_o(
    const bf16* __restrict__ X, const bf16* __restrict__ W,
    const float* __restrict__ bias, float* __restrict__ Yf)
{
  constexpr int N = 1024, K = 1024;
  __shared__ alignas(16) bf16 As[2][8192];
  __shared__ alignas(16) bf16 Bs[2][8192];

  const int tid  = threadIdx.x;
  const int lane = tid & 63;
  const int wv   = tid >> 6;
  const int l15  = lane & 15;
  const int quad = lane >> 4;
  const int wm   = (wv >> 1) * 64;
  const int wn   = (wv & 1) * 64;
  const int nbase = blockIdx.x * 128;
  const int mbase = blockIdx.y * 128;

  f32x4 acc[4][4];
  #pragma unroll
  for (int i = 0; i < 4; ++i)
    #pragma unroll
    for (int j = 0; j < 4; ++j)
      acc[i][j] = (f32x4){0.f, 0.f, 0.f, 0.f};

  const int r8 = lane >> 3;
  const int oc = (lane & 7) ^ r8;
  const size_t lrowA = (size_t)(mbase + wv * 32 + r8);
  const size_t lrowB = (size_t)(nbase + wv * 32 + r8);

#define GSTAGE(BUF, KB)                                                       \
  {                                                                           \
    _Pragma("unroll")                                                         \
    for (int c = 0; c < 4; ++c) {                                             \
      ASYNC_CP16(&As[BUF][(wv * 32 + c * 8) * 64],                            \
                 X + (lrowA + c * 8) * K + (KB) + oc * 8);                    \
      ASYNC_CP16(&Bs[BUF][(wv * 32 + c * 8) * 64],                            \
                 W + (lrowB + c * 8) * K + (KB) + oc * 8);                    \
    }                                                                         \
  }

  GSTAGE(0, 0);
  int cur = 0;
  for (int kb = 0; kb < K; kb += 64) {
    __syncthreads();
    if (kb + 64 < K) GSTAGE(cur ^ 1, kb + 64);
    #pragma unroll
    for (int ks = 0; ks < 2; ++ks) {
      bf16x8 af[4], bfr[4];
      #pragma unroll
      for (int t = 0; t < 4; ++t) {
        const int ma = wm + t * 16 + l15;
        af[t]  = *(const bf16x8*)(&As[cur][(ma * 8 + ((ks * 4 + quad) ^ (ma & 7))) * 8]);
        const int nb = wn + t * 16 + l15;
        bfr[t] = *(const bf16x8*)(&Bs[cur][(nb * 8 + ((ks * 4 + quad) ^ (nb & 7))) * 8]);
      }
      #pragma unroll
      for (int i = 0; i < 4; ++i)
        #pragma unroll
        for (int j = 0; j < 4; ++j)
          acc[i][j] = MFMA_BF16(af[i], bfr[j], acc[i][j]);
    }
    cur ^= 1;
  }
#undef GSTAGE

  #pragma unroll
  for (int i = 0; i < 4; ++i) {
    const int row0 = mbase + wm + i * 16 + quad * 4;
    #pragma unroll
    for (int j = 0; j < 4; ++j) {
      const int col = nbase + wn + j * 16 + l15;
      const float bv2 = bias[col];
      #pragma unroll
      for (int r = 0; r < 4; ++r)
        Yf[(size_t)(row0 + r) * N + col] = acc[i][j][r] + bv2;
    }
  }
}

// ---------------------------------------------------------------------------
// Flash attention, transposed-S, no online max, ASYNC K/V staging (R8
// structure) + ones-MFMA denominator (R11). LDS layouts (R4-verified):
//   Ks[key*8 + oct^swk(key)], swk(key) = (key&3)|(((key>>3)&1)<<2)
//   Vs[hd*8  + oct^(hd&7)]
// R12: 1D grid + XCD-locality swizzle. HW round-robins linear block id
// across the 8 XCDs, so blocks with equal (L&7) share an XCD. Decode:
//   xcd = L&7, ix = L>>3, bh = xcd*8 + (ix>>4), qb = ix&15.
// -> all 16 q-blocks of one (b,h) on one XCD; its K/V (512KB) L2-resident
// (verified: FETCH 140MB -> 25.6MB).
// ---------------------------------------------------------------------------
__global__ __launch_bounds__(256, 4) void attn(
    const bf16* __restrict__ Qb, const bf16* __restrict__ Kb,
    const bf16* __restrict__ Vt, bf16* __restrict__ Ob)
{
  constexpr int S = 2048, D = 1024;
  __shared__ alignas(16) bf16 Ks[2][4096];
  __shared__ alignas(16) bf16 Vs[2][4096];

  const int tid  = threadIdx.x;
  const int lane = tid & 63;
  const int wv   = tid >> 6;
  const int l15  = lane & 15;
  const int q0   = lane >> 4;

  // XCD-locality decode (bijective on [0,1024))
  const int L   = blockIdx.x;
  const int xcd = L & 7;
  const int ix  = L >> 3;
  const int bh  = xcd * 8 + (ix >> 4);
  const int qb  = ix & 15;
  const int b = bh >> 4, h = bh & 15;
  const int qblk = qb * 128 + wv * 32;

  bf16x8 qf[2][2];
  #pragma unroll
  for (int qt = 0; qt < 2; ++qt)
    #pragma unroll
    for (int dh = 0; dh < 2; ++dh)
      qf[qt][dh] = *(const bf16x8*)(
          Qb + (size_t)(b * S + qblk + qt * 16 + l15) * D + h * 64 + dh * 32 + q0 * 8);

  // all-ones A-fragment for the denominator MFMA
  bf16x8 ones;
  #pragma unroll
  for (int i = 0; i < 8; ++i) ones[i] = (bf16)1.0f;

  f32x4 lacc[2];       // lacc[qt][r]: every element = sum_k P[q,k]
  lacc[0] = (f32x4){0.f, 0.f, 0.f, 0.f};
  lacc[1] = (f32x4){0.f, 0.f, 0.f, 0.f};

  f32x4 o[4][2];   // o[ht][qt]
  #pragma unroll
  for (int ht = 0; ht < 4; ++ht)
    #pragma unroll
    for (int qt = 0; qt < 2; ++qt)
      o[ht][qt] = (f32x4){0.f, 0.f, 0.f, 0.f};

  // async staging: wave wv covers rows 16wv..16wv+15 (keys for K, hd for V)
  const int r8a = lane >> 3;                    // 0..7
  const int oc1 = (lane & 7) ^ (r8a & 3);       // K rows 16wv..+7   (bit3=0)
  const int oc2 = oc1 ^ 4;                      // K rows 16wv+8..+15 (bit3=1)
  const int ov  = (lane & 7) ^ r8a;             // V (hd&7 == r8a both halves)
  const bf16* kgw = Kb + (size_t)(b * S) * D + h * 64 + (size_t)(16 * wv) * D;
  const bf16* vgw = Vt + (size_t)(b * 16 + h) * (2048 * 64) + (16 * wv) * 64;

#define STAGE(KC, BUF)                                                        \
  {                                                                           \
    const bf16* ks = kgw + (size_t)(KC) * D;                                  \
    ASYNC_CP16(&Ks[BUF][wv * 1024],       ks + (size_t)r8a * D + oc1 * 8);    \
    ASYNC_CP16(&Ks[BUF][wv * 1024 + 512], ks + (size_t)(8 + r8a) * D + oc2 * 8);\
    const bf16* vs = vgw + (KC) * 64;                                         \
    ASYNC_CP16(&Vs[BUF][wv * 1024],       vs + r8a * 64 + ov * 8);            \
    ASYNC_CP16(&Vs[BUF][wv * 1024 + 512], vs + (8 + r8a) * 64 + ov * 8);      \
  }

  const int kla = 8 * (l15 >> 2) + (l15 & 3);            // permuted key base
  const int swa = (l15 & 3) | (((l15 >> 2) & 1) << 2);   // K-read swizzle
  const int swv = l15 & 7;                               // V-read swizzle

  STAGE(0, 0);

  for (int kc = 0, it = 0; kc < S; kc += 64, ++it) {
    const int cur = it & 1;
    __syncthreads();
    if (kc + 64 < S) STAGE(kc + 64, cur ^ 1);

    __builtin_amdgcn_s_setprio(1);

    f32x4 sc[2][4];
    #pragma unroll
    for (int kt = 0; kt < 4; ++kt) {
      const int key = kla + 4 * (kt & 1) + 32 * (kt >> 1);
      const bf16x8 kf0 = *(const bf16x8*)(&Ks[cur][(key * 8 + (q0 ^ swa)) * 8]);
      const bf16x8 kf1 = *(const bf16x8*)(&Ks[cur][(key * 8 + ((q0 + 4) ^ swa)) * 8]);
      #pragma unroll
      for (int qt = 0; qt < 2; ++qt) {
        f32x4 s = MFMA_BF16(kf0, qf[qt][0], ((f32x4){0.f, 0.f, 0.f, 0.f}));
        sc[qt][kt] = MFMA_BF16(kf1, qf[qt][1], s);
      }
    }

    bf16x8 pb[2][2];
    #pragma unroll
    for (int qt = 0; qt < 2; ++qt) {
      #pragma unroll
      for (int kt = 0; kt < 4; ++kt)
        #pragma unroll
        for (int r = 0; r < 4; ++r)
          pb[qt][kt >> 1][(kt & 1) * 4 + r] = (bf16)EXP2F(sc[qt][kt][r]);
    }

    // denominator on the matrix pipe: lacc[qt] += ones x pb[qt][half]
    #pragma unroll
    for (int qt = 0; qt < 2; ++qt) {
      lacc[qt] = MFMA_BF16(ones, pb[qt][0], lacc[qt]);
      lacc[qt] = MFMA_BF16(ones, pb[qt][1], lacc[qt]);
    }

    #pragma unroll
    for (int ht = 0; ht < 4; ++ht) {
      const int row = ht * 16 + l15;
      const bf16x8 vf0 = *(const bf16x8*)(&Vs[cur][(row * 8 + (q0 ^ swv)) * 8]);
      const bf16x8 vf1 = *(const bf16x8*)(&Vs[cur][(row * 8 + ((q0 + 4) ^ swv)) * 8]);
      #pragma unroll
      for (int qt = 0; qt < 2; ++qt) {
        o[ht][qt] = MFMA_BF16(vf0, pb[qt][0], o[ht][qt]);
        o[ht][qt] = MFMA_BF16(vf1, pb[qt][1], o[ht][qt]);
      }
    }

    __builtin_amdgcn_s_setprio(0);
  }
#undef STAGE

  #pragma unroll
  for (int qt = 0; qt < 2; ++qt) {
    const float inv = 1.0f / lacc[qt][0];   // every lane holds full l for its q=l15
    bf16* orow = Ob + (size_t)(b * S + qblk + qt * 16 + l15) * D + h * 64 + q0 * 4;
    #pragma unroll
    for (int ht = 0; ht < 4; ++ht) {
      bf16x4 w;
      w[0] = (bf16)(o[ht][qt][0] * inv);
      w[1] = (bf16)(o[ht][qt][1] * inv);
      w[2] = (bf16)(o[ht][qt][2] * inv);
      w[3] = (bf16)(o[ht][qt][3] * inv);
      *(bf16x4*)(orow + ht * 16) = w;
    }
  }
}

// ---------------------------------------------------------------------------
extern "C" void kernel_launch(void* const* d_in, const int* in_sizes, int n_in,
                              void* d_out, int out_size, void* d_ws, size_t ws_size,
                              hipStream_t stream)
{
  const float* x  = (const float*)d_in[0];
  const float* Wq = (const float*)d_in[1];
  const float* bq = (const float*)d_in[2];
  const float* Wk = (const float*)d_in[3];
  const float* bk = (const float*)d_in[4];
  const float* Wv = (const float*)d_in[5];
  const float* bv = (const float*)d_in[6];
  const float* Wo = (const float*)d_in[7];
  const float* bo = (const float*)d_in[8];
  float* out = (float*)d_out;

  const size_t NX = (size_t)8192 * 1024;
  const size_t NW = (size_t)1024 * 1024;

  bf16* xb  = (bf16*)d_ws;
  bf16* Wqb = xb  + NX;
  bf16* Wkb = Wqb + NW;
  bf16* Wvb = Wkb + NW;
  bf16* Wob = Wvb + NW;
  bf16* Qb  = Wob + NW;
  bf16* Kb  = Qb  + NX;
  bf16* Vt  = Kb  + NX;   // chunk-major [BH][S/64][HD][64]
  bf16* Ctx = Vt  + NX;

  const float QSCALE = 0.18033688011112042f;  // 0.125 * log2(e)

  dim3 bc(256, 1, 1);
  hipLaunchKernelGGL(cvt5, dim3(1024, 5, 1), bc, 0, stream,
                     x, xb, (int)NX, Wq, Wqb, (int)NW, Wk, Wkb, (int)NW,
                     Wv, Wvb, (int)NW, Wo, Wob, (int)NW);

  hipLaunchKernelGGL(gemm_qkv, dim3(24, 64, 1), bc, 0, stream,
                     xb, Wqb, Wkb, Wvb, bq, bk, bv, Qb, Kb, Vt, QSCALE);

  hipLaunchKernelGGL(attn, dim3(1024, 1, 1), bc, 0, stream, Qb, Kb, Vt, Ctx);

  hipLaunchKernelGGL(gemm_o, dim3(8, 64, 1), bc, 0, stream, Ctx, Wob, bo, out);
}

// Round 8
// 286.679 us; speedup vs baseline: 1.0141x; 1.0141x over previous
//
#include <hip/hip_runtime.h>
#include <hip/hip_bf16.h>
#include <stdint.h>

// ---------------------------------------------------------------------------
// SelfAttention: B=4 S=2048 D=1024 H=16 HD=64. I/O dtype: FLOAT32.
//   0) cvt: x, Wq, Wk, Wv, Wo  f32 -> bf16
//   1) gemm_qkv R16: BK=64 double-buffer with RAW s_barrier + COUNTED
//      vmcnt(8) (T4). R15 proved __syncthreads() drains vmcnt(0) at every
//      barrier -> prefetch window = compute phase only (~300cy < 600cy
//      latency). Counted waits keep the next-tile loads in flight across
//      the barrier; steady-state window = full iteration.
//      Race safety: each wave's vmcnt(8)-before-barrier retires its OLDEST
//      8 loads (= the tile about to be read); barrier orders all waves'
//      reads after all waves' retirement. vmcnt(0) on the final iter
//      (no new stage issued -> count would be wrong).
//   2) attn R12 (unchanged, 79.5us verified): LDS dbuf ASYNC staging +
//      ones-MFMA denominator + XCD-locality swizzle (FETCH 140->25MB).
//   3) gemm_o R16: same counted-vmcnt dbuf.
// ---------------------------------------------------------------------------

typedef __bf16 bf16;
typedef __bf16 bf16x8 __attribute__((ext_vector_type(8)));
typedef __bf16 bf16x4 __attribute__((ext_vector_type(4)));
typedef float  f32x4  __attribute__((ext_vector_type(4)));

#define MFMA_BF16(A, B, C) __builtin_amdgcn_mfma_f32_16x16x32_bf16(A, B, C, 0, 0, 0)
#define EXP2F(x) __builtin_amdgcn_exp2f(x)

#define ASYNC_CP16(DST_LDS, SRC_G)                                            \
  __builtin_amdgcn_global_load_lds(                                           \
      (__attribute__((address_space(1))) void*)(SRC_G),                       \
      (__attribute__((address_space(3))) void*)(DST_LDS), 16, 0, 0)

// ---------------------------------------------------------------------------
__global__ __launch_bounds__(256) void cvt5(
    const float* __restrict__ s0, bf16* __restrict__ d0, int n0,
    const float* __restrict__ s1, bf16* __restrict__ d1, int n1,
    const float* __restrict__ s2, bf16* __restrict__ d2, int n2,
    const float* __restrict__ s3, bf16* __restrict__ d3, int n3,
    const float* __restrict__ s4, bf16* __restrict__ d4, int n4)
{
  const float* s; bf16* d; int n;
  switch (blockIdx.y) {
    case 0: s = s0; d = d0; n = n0; break;
    case 1: s = s1; d = d1; n = n1; break;
    case 2: s = s2; d = d2; n = n2; break;
    case 3: s = s3; d = d3; n = n3; break;
    default: s = s4; d = d4; n = n4; break;
  }
  const int stride = gridDim.x * blockDim.x * 4;
  for (int i = (blockIdx.x * blockDim.x + threadIdx.x) * 4; i < n; i += stride) {
    const float4 v = *(const float4*)(s + i);
    bf16x4 o;
    o[0] = (bf16)v.x; o[1] = (bf16)v.y; o[2] = (bf16)v.z; o[3] = (bf16)v.w;
    *(bf16x4*)(d + i) = o;
  }
}

// ---------------------------------------------------------------------------
// Fused QKV GEMM. grid (24,64): blockIdx.x>>3 selects {Q,K,V}; &7 is nbase.
// V stored chunk-major: Vt[bh][s>>6][hd][s&63].
// R16: BK=64 dbuf + raw-barrier/counted-vmcnt pipeline.
// ---------------------------------------------------------------------------
__global__ __launch_bounds__(256, 4) void gemm_qkv(
    const bf16* __restrict__ X,
    const bf16* __restrict__ Wq, const bf16* __restrict__ Wk,
    const bf16* __restrict__ Wv,
    const float* __restrict__ bq, const float* __restrict__ bk,
    const float* __restrict__ bv,
    bf16* __restrict__ Qo, bf16* __restrict__ Ko, bf16* __restrict__ Vo,
    float qscale)
{
  constexpr int N = 1024, K = 1024;
  __shared__ alignas(16) bf16 As[2][8192];
  __shared__ alignas(16) bf16 Bs[2][8192];

  const int sel = blockIdx.x >> 3;          // 0=Q 1=K 2=V
  const bf16*  W    = (sel == 0) ? Wq : (sel == 1) ? Wk : Wv;
  const float* bias = (sel == 0) ? bq : (sel == 1) ? bk : bv;
  bf16*        Y    = (sel == 0) ? Qo : (sel == 1) ? Ko : Vo;
  const float scale = (sel == 0) ? qscale : 1.0f;

  const int tid  = threadIdx.x;
  const int lane = tid & 63;
  const int wv   = tid >> 6;
  const int l15  = lane & 15;
  const int quad = lane >> 4;
  const int wm   = (wv >> 1) * 64;
  const int wn   = (wv & 1) * 64;
  const int nbase = (blockIdx.x & 7) * 128;
  const int mbase = blockIdx.y * 128;

  f32x4 acc[4][4];
  #pragma unroll
  for (int i = 0; i < 4; ++i)
    #pragma unroll
    for (int j = 0; j < 4; ++j)
      acc[i][j] = (f32x4){0.f, 0.f, 0.f, 0.f};

  const int r8 = lane >> 3;
  const int oc = (lane & 7) ^ r8;
  const size_t lrowA = (size_t)(mbase + wv * 32 + r8);
  const size_t lrowB = (size_t)(nbase + wv * 32 + r8);

#define GSTAGE(BUF, KB)                                                       \
  {                                                                           \
    _Pragma("unroll")                                                         \
    for (int c = 0; c < 4; ++c) {                                             \
      ASYNC_CP16(&As[BUF][(wv * 32 + c * 8) * 64],                            \
                 X + (lrowA + c * 8) * K + (KB) + oc * 8);                    \
      ASYNC_CP16(&Bs[BUF][(wv * 32 + c * 8) * 64],                            \
                 W + (lrowB + c * 8) * K + (KB) + oc * 8);                    \
    }                                                                         \
  }

  GSTAGE(0, 0);
  int cur = 0;
  for (int kb = 0; kb < K; kb += 64) {
    if (kb + 64 < K) {
      GSTAGE(cur ^ 1, kb + 64);                       // 8 new loads in flight
      asm volatile("s_waitcnt vmcnt(8)" ::: "memory"); // oldest 8 (tile cur) landed
    } else {
      asm volatile("s_waitcnt vmcnt(0)" ::: "memory"); // final tile: drain all
    }
    __builtin_amdgcn_s_barrier();                      // cur visible to all waves
    asm volatile("" ::: "memory");
    #pragma unroll
    for (int ks = 0; ks < 2; ++ks) {
      bf16x8 af[4], bfr[4];
      #pragma unroll
      for (int t = 0; t < 4; ++t) {
        const int ma = wm + t * 16 + l15;
        af[t]  = *(const bf16x8*)(&As[cur][(ma * 8 + ((ks * 4 + quad) ^ (ma & 7))) * 8]);
        const int nb = wn + t * 16 + l15;
        bfr[t] = *(const bf16x8*)(&Bs[cur][(nb * 8 + ((ks * 4 + quad) ^ (nb & 7))) * 8]);
      }
      #pragma unroll
      for (int i = 0; i < 4; ++i)
        #pragma unroll
        for (int j = 0; j < 4; ++j)
          acc[i][j] = MFMA_BF16(af[i], bfr[j], acc[i][j]);
    }
    asm volatile("" ::: "memory");
    __builtin_amdgcn_s_barrier();                      // all reads of cur done
    cur ^= 1;
  }
#undef GSTAGE

  #pragma unroll
  for (int i = 0; i < 4; ++i) {
    const int row0 = mbase + wm + i * 16 + quad * 4;
    #pragma unroll
    for (int j = 0; j < 4; ++j) {
      const int col = nbase + wn + j * 16 + l15;
      const float bv2 = bias[col];
      #pragma unroll
      for (int r = 0; r < 4; ++r) {
        const float v = (acc[i][j][r] + bv2) * scale;
        const int row = row0 + r;
        if (sel != 2) {
          Y[(size_t)row * N + col] = (bf16)v;
        } else {
          const int bb = row >> 11, s  = row & 2047;
          const int hh = col >> 6,  hd = col & 63;
          // chunk-major: [bh][s>>6][hd][s&63]
          Y[(size_t)(bb * 16 + hh) * (2048 * 64) + (size_t)(s >> 6) * 4096 +
            hd * 64 + (s & 63)] = (bf16)v;
        }
      }
    }
  }
}

// ---------------------------------------------------------------------------
// O-projection GEMM (f32 out), 128x128 tile, grid (8,64).
// R16: same counted-vmcnt dbuf pipeline.
// ---------------------------------------------------------------------------
__global__ __launch_bounds__(256, 4) void gemm_o(
    const bf16* __restrict__ X, const bf16* __restrict__ W,
    const float* __restrict__ bias, float* __restrict__ Yf)
{
  constexpr int N = 1024, K = 1024;
  __shared__ alignas(16) bf16 As[2][8192];
  __shared__ alignas(16) bf16 Bs[2][8192];

  const int tid  = threadIdx.x;
  const int lane = tid & 63;
  const int wv   = tid >> 6;
  const int l15  = lane & 15;
  const int quad = lane >> 4;
  const int wm   = (wv >> 1) * 64;
  const int wn   = (wv & 1) * 64;
  const int nbase = blockIdx.x * 128;
  const int mbase = blockIdx.y * 128;

  f32x4 acc[4][4];
  #pragma unroll
  for (int i = 0; i < 4; ++i)
    #pragma unroll
    for (int j = 0; j < 4; ++j)
      acc[i][j] = (f32x4){0.f, 0.f, 0.f, 0.f};

  const int r8 = lane >> 3;
  const int oc = (lane & 7) ^ r8;
  const size_t lrowA = (size_t)(mbase + wv * 32 + r8);
  const size_t lrowB = (size_t)(nbase + wv * 32 + r8);

#define GSTAGE(BUF, KB)                                                       \
  {                                                                           \
    _Pragma("unroll")                                                         \
    for (int c = 0; c < 4; ++c) {                                             \
      ASYNC_CP16(&As[BUF][(wv * 32 + c * 8) * 64],                            \
                 X + (lrowA + c * 8) * K + (KB) + oc * 8);                    \
      ASYNC_CP16(&Bs[BUF][(wv * 32 + c * 8) * 64],                            \
                 W + (lrowB + c * 8) * K + (KB) + oc * 8);                    \
    }                                                                         \
  }

  GSTAGE(0, 0);
  int cur = 0;
  for (int kb = 0; kb < K; kb += 64) {
    if (kb + 64 < K) {
      GSTAGE(cur ^ 1, kb + 64);
      asm volatile("s_waitcnt vmcnt(8)" ::: "memory");
    } else {
      asm volatile("s_waitcnt vmcnt(0)" ::: "memory");
    }
    __builtin_amdgcn_s_barrier();
    asm volatile("" ::: "memory");
    #pragma unroll
    for (int ks = 0; ks < 2; ++ks) {
      bf16x8 af[4], bfr[4];
      #pragma unroll
      for (int t = 0; t < 4; ++t) {
        const int ma = wm + t * 16 + l15;
        af[t]  = *(const bf16x8*)(&As[cur][(ma * 8 + ((ks * 4 + quad) ^ (ma & 7))) * 8]);
        const int nb = wn + t * 16 + l15;
        bfr[t] = *(const bf16x8*)(&Bs[cur][(nb * 8 + ((ks * 4 + quad) ^ (nb & 7))) * 8]);
      }
      #pragma unroll
      for (int i = 0; i < 4; ++i)
        #pragma unroll
        for (int j = 0; j < 4; ++j)
          acc[i][j] = MFMA_BF16(af[i], bfr[j], acc[i][j]);
    }
    asm volatile("" ::: "memory");
    __builtin_amdgcn_s_barrier();
    cur ^= 1;
  }
#undef GSTAGE

  #pragma unroll
  for (int i = 0; i < 4; ++i) {
    const int row0 = mbase + wm + i * 16 + quad * 4;
    #pragma unroll
    for (int j = 0; j < 4; ++j) {
      const int col = nbase + wn + j * 16 + l15;
      const float bv2 = bias[col];
      #pragma unroll
      for (int r = 0; r < 4; ++r)
        Yf[(size_t)(row0 + r) * N + col] = acc[i][j][r] + bv2;
    }
  }
}

// ---------------------------------------------------------------------------
// Flash attention, transposed-S, no online max, ASYNC K/V staging (R8
// structure) + ones-MFMA denominator (R11). LDS layouts (R4-verified):
//   Ks[key*8 + oct^swk(key)], swk(key) = (key&3)|(((key>>3)&1)<<2)
//   Vs[hd*8  + oct^(hd&7)]
// R12: 1D grid + XCD-locality swizzle. Decode:
//   xcd = L&7, ix = L>>3, bh = xcd*8 + (ix>>4), qb = ix&15.
// -> all 16 q-blocks of one (b,h) on one XCD; its K/V (512KB) L2-resident
// (verified: FETCH 140MB -> 25.6MB).
// ---------------------------------------------------------------------------
__global__ __launch_bounds__(256, 4) void attn(
    const bf16* __restrict__ Qb, const bf16* __restrict__ Kb,
    const bf16* __restrict__ Vt, bf16* __restrict__ Ob)
{
  constexpr int S = 2048, D = 1024;
  __shared__ alignas(16) bf16 Ks[2][4096];
  __shared__ alignas(16) bf16 Vs[2][4096];

  const int tid  = threadIdx.x;
  const int lane = tid & 63;
  const int wv   = tid >> 6;
  const int l15  = lane & 15;
  const int q0   = lane >> 4;

  // XCD-locality decode (bijective on [0,1024))
  const int L   = blockIdx.x;
  const int xcd = L & 7;
  const int ix  = L >> 3;
  const int bh  = xcd * 8 + (ix >> 4);
  const int qb  = ix & 15;
  const int b = bh >> 4, h = bh & 15;
  const int qblk = qb * 128 + wv * 32;

  bf16x8 qf[2][2];
  #pragma unroll
  for (int qt = 0; qt < 2; ++qt)
    #pragma unroll
    for (int dh = 0; dh < 2; ++dh)
      qf[qt][dh] = *(const bf16x8*)(
          Qb + (size_t)(b * S + qblk + qt * 16 + l15) * D + h * 64 + dh * 32 + q0 * 8);

  // all-ones A-fragment for the denominator MFMA
  bf16x8 ones;
  #pragma unroll
  for (int i = 0; i < 8; ++i) ones[i] = (bf16)1.0f;

  f32x4 lacc[2];       // lacc[qt][r]: every element = sum_k P[q,k]
  lacc[0] = (f32x4){0.f, 0.f, 0.f, 0.f};
  lacc[1] = (f32x4){0.f, 0.f, 0.f, 0.f};

  f32x4 o[4][2];   // o[ht][qt]
  #pragma unroll
  for (int ht = 0; ht < 4; ++ht)
    #pragma unroll
    for (int qt = 0; qt < 2; ++qt)
      o[ht][qt] = (f32x4){0.f, 0.f, 0.f, 0.f};

  // async staging: wave wv covers rows 16wv..16wv+15 (keys for K, hd for V)
  const int r8a = lane >> 3;                    // 0..7
  const int oc1 = (lane & 7) ^ (r8a & 3);       // K rows 16wv..+7   (bit3=0)
  const int oc2 = oc1 ^ 4;                      // K rows 16wv+8..+15 (bit3=1)
  const int ov  = (lane & 7) ^ r8a;             // V (hd&7 == r8a both halves)
  const bf16* kgw = Kb + (size_t)(b * S) * D + h * 64 + (size_t)(16 * wv) * D;
  const bf16* vgw = Vt + (size_t)(b * 16 + h) * (2048 * 64) + (16 * wv) * 64;

#define STAGE(KC, BUF)                                                        \
  {                                                                           \
    const bf16* ks = kgw + (size_t)(KC) * D;                                  \
    ASYNC_CP16(&Ks[BUF][wv * 1024],       ks + (size_t)r8a * D + oc1 * 8);    \
    ASYNC_CP16(&Ks[BUF][wv * 1024 + 512], ks + (size_t)(8 + r8a) * D + oc2 * 8);\
    const bf16* vs = vgw + (KC) * 64;                                         \
    ASYNC_CP16(&Vs[BUF][wv * 1024],       vs + r8a * 64 + ov * 8);            \
    ASYNC_CP16(&Vs[BUF][wv * 1024 + 512], vs + (8 + r8a) * 64 + ov * 8);      \
  }

  const int kla = 8 * (l15 >> 2) + (l15 & 3);            // permuted key base
  const int swa = (l15 & 3) | (((l15 >> 2) & 1) << 2);   // K-read swizzle
  const int swv = l15 & 7;                               // V-read swizzle

  STAGE(0, 0);

  for (int kc = 0, it = 0; kc < S; kc += 64, ++it) {
    const int cur = it & 1;
    __syncthreads();
    if (kc + 64 < S) STAGE(kc + 64, cur ^ 1);

    __builtin_amdgcn_s_setprio(1);

    f32x4 sc[2][4];
    #pragma unroll
    for (int kt = 0; kt < 4; ++kt) {
      const int key = kla + 4 * (kt & 1) + 32 * (kt >> 1);
      const bf16x8 kf0 = *(const bf16x8*)(&Ks[cur][(key * 8 + (q0 ^ swa)) * 8]);
      const bf16x8 kf1 = *(const bf16x8*)(&Ks[cur][(key * 8 + ((q0 + 4) ^ swa)) * 8]);
      #pragma unroll
      for (int qt = 0; qt < 2; ++qt) {
        f32x4 s = MFMA_BF16(kf0, qf[qt][0], ((f32x4){0.f, 0.f, 0.f, 0.f}));
        sc[qt][kt] = MFMA_BF16(kf1, qf[qt][1], s);
      }
    }

    bf16x8 pb[2][2];
    #pragma unroll
    for (int qt = 0; qt < 2; ++qt) {
      #pragma unroll
      for (int kt = 0; kt < 4; ++kt)
        #pragma unroll
        for (int r = 0; r < 4; ++r)
          pb[qt][kt >> 1][(kt & 1) * 4 + r] = (bf16)EXP2F(sc[qt][kt][r]);
    }

    // denominator on the matrix pipe: lacc[qt] += ones x pb[qt][half]
    #pragma unroll
    for (int qt = 0; qt < 2; ++qt) {
      lacc[qt] = MFMA_BF16(ones, pb[qt][0], lacc[qt]);
      lacc[qt] = MFMA_BF16(ones, pb[qt][1], lacc[qt]);
    }

    #pragma unroll
    for (int ht = 0; ht < 4; ++ht) {
      const int row = ht * 16 + l15;
      const bf16x8 vf0 = *(const bf16x8*)(&Vs[cur][(row * 8 + (q0 ^ swv)) * 8]);
      const bf16x8 vf1 = *(const bf16x8*)(&Vs[cur][(row * 8 + ((q0 + 4) ^ swv)) * 8]);
      #pragma unroll
      for (int qt = 0; qt < 2; ++qt) {
        o[ht][qt] = MFMA_BF16(vf0, pb[qt][0], o[ht][qt]);
        o[ht][qt] = MFMA_BF16(vf1, pb[qt][1], o[ht][qt]);
      }
    }

    __builtin_amdgcn_s_setprio(0);
  }
#undef STAGE

  #pragma unroll
  for (int qt = 0; qt < 2; ++qt) {
    const float inv = 1.0f / lacc[qt][0];   // every lane holds full l for its q=l15
    bf16* orow = Ob + (size_t)(b * S + qblk + qt * 16 + l15) * D + h * 64 + q0 * 4;
    #pragma unroll
    for (int ht = 0; ht < 4; ++ht) {
      bf16x4 w;
      w[0] = (bf16)(o[ht][qt][0] * inv);
      w[1] = (bf16)(o[ht][qt][1] * inv);
      w[2] = (bf16)(o[ht][qt][2] * inv);
      w[3] = (bf16)(o[ht][qt][3] * inv);
      *(bf16x4*)(orow + ht * 16) = w;
    }
  }
}

// ---------------------------------------------------------------------------
extern "C" void kernel_launch(void* const* d_in, const int* in_sizes, int n_in,
                              void* d_out, int out_size, void* d_ws, size_t ws_size,
                              hipStream_t stream)
{
  const float* x  = (const float*)d_in[0];
  const float* Wq = (const float*)d_in[1];
  const float* bq = (const float*)d_in[2];
  const float* Wk = (const float*)d_in[3];
  const float* bk = (const float*)d_in[4];
  const float* Wv = (const float*)d_in[5];
  const float* bv = (const float*)d_in[6];
  const float* Wo = (const float*)d_in[7];
  const float* bo = (const float*)d_in[8];
  float* out = (float*)d_out;

  const size_t NX = (size_t)8192 * 1024;
  const size_t NW = (size_t)1024 * 1024;

  bf16* xb  = (bf16*)d_ws;
  bf16* Wqb = xb  + NX;
  bf16* Wkb = Wqb + NW;
  bf16* Wvb = Wkb + NW;
  bf16* Wob = Wvb + NW;
  bf16* Qb  = Wob + NW;
  bf16* Kb  = Qb  + NX;
  bf16* Vt  = Kb  + NX;   // chunk-major [BH][S/64][HD][64]
  bf16* Ctx = Vt  + NX;

  const float QSCALE = 0.18033688011112042f;  // 0.125 * log2(e)

  dim3 bc(256, 1, 1);
  hipLaunchKernelGGL(cvt5, dim3(1024, 5, 1), bc, 0, stream,
                     x, xb, (int)NX, Wq, Wqb, (int)NW, Wk, Wkb, (int)NW,
                     Wv, Wvb, (int)NW, Wo, Wob, (int)NW);

  hipLaunchKernelGGL(gemm_qkv, dim3(24, 64, 1), bc, 0, stream,
                     xb, Wqb, Wkb, Wvb, bq, bk, bv, Qb, Kb, Vt, QSCALE);

  hipLaunchKernelGGL(attn, dim3(1024, 1, 1), bc, 0, stream, Qb, Kb, Vt, Ctx);

  hipLaunchKernelGGL(gemm_o, dim3(8, 64, 1), bc, 0, stream, Ctx, Wob, bo, out);
}

// Round 9
// 271.573 us; speedup vs baseline: 1.0705x; 1.0556x over previous
//
#include <hip/hip_runtime.h>
#include <hip/hip_bf16.h>
#include <stdint.h>

// ---------------------------------------------------------------------------
// SelfAttention: B=4 S=2048 D=1024 H=16 HD=64. I/O dtype: FLOAT32.
//   0) cvt: x, Wq, Wk, Wv, Wo  f32 -> bf16
//   1) gemm_qkv R17 = R12 exact (BK=64 single-buffer, grid (24,64), 80.5us
//      verified). All pipelining variants (R13 BK=32 dbuf, R15 syncthreads
//      dbuf, R16 counted-vmcnt dbuf) and both XCD swizzles lost to this.
//   2) attn R12 (unchanged, 79.5us verified): LDS dbuf ASYNC staging +
//      ones-MFMA denominator + XCD-locality swizzle (FETCH 140->25MB).
//   3) gemm_o R17 = R14 exact (1D grid 512 + XCD swizzle): R14-vs-R12
//      total-delta isolated ~17us gain for this kernel (8 blocks share a
//      512KB Ctx row-panel -> single-XCD L2 residency).
// ---------------------------------------------------------------------------

typedef __bf16 bf16;
typedef __bf16 bf16x8 __attribute__((ext_vector_type(8)));
typedef __bf16 bf16x4 __attribute__((ext_vector_type(4)));
typedef float  f32x4  __attribute__((ext_vector_type(4)));

#define MFMA_BF16(A, B, C) __builtin_amdgcn_mfma_f32_16x16x32_bf16(A, B, C, 0, 0, 0)
#define EXP2F(x) __builtin_amdgcn_exp2f(x)

#define ASYNC_CP16(DST_LDS, SRC_G)                                            \
  __builtin_amdgcn_global_load_lds(                                           \
      (__attribute__((address_space(1))) void*)(SRC_G),                       \
      (__attribute__((address_space(3))) void*)(DST_LDS), 16, 0, 0)

// ---------------------------------------------------------------------------
__global__ __launch_bounds__(256) void cvt5(
    const float* __restrict__ s0, bf16* __restrict__ d0, int n0,
    const float* __restrict__ s1, bf16* __restrict__ d1, int n1,
    const float* __restrict__ s2, bf16* __restrict__ d2, int n2,
    const float* __restrict__ s3, bf16* __restrict__ d3, int n3,
    const float* __restrict__ s4, bf16* __restrict__ d4, int n4)
{
  const float* s; bf16* d; int n;
  switch (blockIdx.y) {
    case 0: s = s0; d = d0; n = n0; break;
    case 1: s = s1; d = d1; n = n1; break;
    case 2: s = s2; d = d2; n = n2; break;
    case 3: s = s3; d = d3; n = n3; break;
    default: s = s4; d = d4; n = n4; break;
  }
  const int stride = gridDim.x * blockDim.x * 4;
  for (int i = (blockIdx.x * blockDim.x + threadIdx.x) * 4; i < n; i += stride) {
    const float4 v = *(const float4*)(s + i);
    bf16x4 o;
    o[0] = (bf16)v.x; o[1] = (bf16)v.y; o[2] = (bf16)v.z; o[3] = (bf16)v.w;
    *(bf16x4*)(d + i) = o;
  }
}

// ---------------------------------------------------------------------------
// Fused QKV GEMM. grid (24,64): blockIdx.x>>3 selects {Q,K,V}; &7 is nbase.
// V stored chunk-major: Vt[bh][s>>6][hd][s&63].  (R12 exact.)
// ---------------------------------------------------------------------------
__global__ __launch_bounds__(256, 4) void gemm_qkv(
    const bf16* __restrict__ X,
    const bf16* __restrict__ Wq, const bf16* __restrict__ Wk,
    const bf16* __restrict__ Wv,
    const float* __restrict__ bq, const float* __restrict__ bk,
    const float* __restrict__ bv,
    bf16* __restrict__ Qo, bf16* __restrict__ Ko, bf16* __restrict__ Vo,
    float qscale)
{
  constexpr int N = 1024, K = 1024;
  __shared__ alignas(16) bf16 As[8192];
  __shared__ alignas(16) bf16 Bs[8192];

  const int sel = blockIdx.x >> 3;          // 0=Q 1=K 2=V
  const bf16*  W    = (sel == 0) ? Wq : (sel == 1) ? Wk : Wv;
  const float* bias = (sel == 0) ? bq : (sel == 1) ? bk : bv;
  bf16*        Y    = (sel == 0) ? Qo : (sel == 1) ? Ko : Vo;
  const float scale = (sel == 0) ? qscale : 1.0f;

  const int tid  = threadIdx.x;
  const int lane = tid & 63;
  const int wv   = tid >> 6;
  const int l15  = lane & 15;
  const int quad = lane >> 4;
  const int wm   = (wv >> 1) * 64;
  const int wn   = (wv & 1) * 64;
  const int nbase = (blockIdx.x & 7) * 128;
  const int mbase = blockIdx.y * 128;

  f32x4 acc[4][4];
  #pragma unroll
  for (int i = 0; i < 4; ++i)
    #pragma unroll
    for (int j = 0; j < 4; ++j)
      acc[i][j] = (f32x4){0.f, 0.f, 0.f, 0.f};

  const int r8 = lane >> 3;
  const int oc = (lane & 7) ^ r8;
  const size_t lrowA = (size_t)(mbase + wv * 32 + r8);
  const size_t lrowB = (size_t)(nbase + wv * 32 + r8);

  for (int kb = 0; kb < K; kb += 64) {
    #pragma unroll
    for (int c = 0; c < 4; ++c) {
      ASYNC_CP16(As + (wv * 32 + c * 8) * 64, X + (lrowA + c * 8) * K + kb + oc * 8);
      ASYNC_CP16(Bs + (wv * 32 + c * 8) * 64, W + (lrowB + c * 8) * K + kb + oc * 8);
    }
    __syncthreads();
    #pragma unroll
    for (int ks = 0; ks < 2; ++ks) {
      bf16x8 af[4], bfr[4];
      #pragma unroll
      for (int t = 0; t < 4; ++t) {
        const int ma = wm + t * 16 + l15;
        af[t]  = *(const bf16x8*)(As + (ma * 8 + ((ks * 4 + quad) ^ (ma & 7))) * 8);
        const int nb = wn + t * 16 + l15;
        bfr[t] = *(const bf16x8*)(Bs + (nb * 8 + ((ks * 4 + quad) ^ (nb & 7))) * 8);
      }
      #pragma unroll
      for (int i = 0; i < 4; ++i)
        #pragma unroll
        for (int j = 0; j < 4; ++j)
          acc[i][j] = MFMA_BF16(af[i], bfr[j], acc[i][j]);
    }
    __syncthreads();
  }

  #pragma unroll
  for (int i = 0; i < 4; ++i) {
    const int row0 = mbase + wm + i * 16 + quad * 4;
    #pragma unroll
    for (int j = 0; j < 4; ++j) {
      const int col = nbase + wn + j * 16 + l15;
      const float bv2 = bias[col];
      #pragma unroll
      for (int r = 0; r < 4; ++r) {
        const float v = (acc[i][j][r] + bv2) * scale;
        const int row = row0 + r;
        if (sel != 2) {
          Y[(size_t)row * N + col] = (bf16)v;
        } else {
          const int bb = row >> 11, s  = row & 2047;
          const int hh = col >> 6,  hd = col & 63;
          // chunk-major: [bh][s>>6][hd][s&63]
          Y[(size_t)(bb * 16 + hh) * (2048 * 64) + (size_t)(s >> 6) * 4096 +
            hd * 64 + (s & 63)] = (bf16)v;
        }
      }
    }
  }
}

// ---------------------------------------------------------------------------
// O-projection GEMM (f32 out), 128x128 tile, 1D grid 512 with XCD swizzle
// (R14 exact): xcd = id&7, j = id>>3 (0..63), y = (j>>3)*8 + xcd, x = j&7.
// All 8 n-blocks of one Ctx row-panel share an XCD (512KB L2-resident).
// ---------------------------------------------------------------------------
__global__ __launch_bounds__(256) void gemm_o(
    const bf16* __restrict__ X, const bf16* __restrict__ W,
    const float* __restrict__ bias, float* __restrict__ Yf)
{
  constexpr int N = 1024, K = 1024;
  __shared__ alignas(16) bf16 As[8192];
  __shared__ alignas(16) bf16 Bs[8192];

  const int id  = blockIdx.x;
  const int xcd = id & 7;
  const int j   = id >> 3;            // 0..63
  const int y   = (j >> 3) * 8 + xcd; // 0..63
  const int xb  = j & 7;

  const int tid  = threadIdx.x;
  const int lane = tid & 63;
  const int wv   = tid >> 6;
  const int l15  = lane & 15;
  const int quad = lane >> 4;
  const int wm   = (wv >> 1) * 64;
  const int wn   = (wv & 1) * 64;
  const int nbase = xb * 128;
  const int mbase = y * 128;

  f32x4 acc[4][4];
  #pragma unroll
  for (int i = 0; i < 4; ++i)
    #pragma unroll
    for (int j2 = 0; j2 < 4; ++j2)
      acc[i][j2] = (f32x4){0.f, 0.f, 0.f, 0.f};

  const int r8 = lane >> 3;
  const int oc = (lane & 7) ^ r8;
  const size_t lrowA = (size_t)(mbase + wv * 32 + r8);
  const size_t lrowB = (size_t)(nbase + wv * 32 + r8);

  for (int kb = 0; kb < K; kb += 64) {
    #pragma unroll
    for (int c = 0; c < 4; ++c) {
      ASYNC_CP16(As + (wv * 32 + c * 8) * 64, X + (lrowA + c * 8) * K + kb + oc * 8);
      ASYNC_CP16(Bs + (wv * 32 + c * 8) * 64, W + (lrowB + c * 8) * K + kb + oc * 8);
    }
    __syncthreads();
    #pragma unroll
    for (int ks = 0; ks < 2; ++ks) {
      bf16x8 af[4], bfr[4];
      #pragma unroll
      for (int t = 0; t < 4; ++t) {
        const int ma = wm + t * 16 + l15;
        af[t]  = *(const bf16x8*)(As + (ma * 8 + ((ks * 4 + quad) ^ (ma & 7))) * 8);
        const int nb = wn + t * 16 + l15;
        bfr[t] = *(const bf16x8*)(Bs + (nb * 8 + ((ks * 4 + quad) ^ (nb & 7))) * 8);
      }
      #pragma unroll
      for (int i = 0; i < 4; ++i)
        #pragma unroll
        for (int j2 = 0; j2 < 4; ++j2)
          acc[i][j2] = MFMA_BF16(af[i], bfr[j2], acc[i][j2]);
    }
    __syncthreads();
  }

  #pragma unroll
  for (int i = 0; i < 4; ++i) {
    const int row0 = mbase + wm + i * 16 + quad * 4;
    #pragma unroll
    for (int j2 = 0; j2 < 4; ++j2) {
      const int col = nbase + wn + j2 * 16 + l15;
      const float bv2 = bias[col];
      #pragma unroll
      for (int r = 0; r < 4; ++r)
        Yf[(size_t)(row0 + r) * N + col] = acc[i][j2][r] + bv2;
    }
  }
}

// ---------------------------------------------------------------------------
// Flash attention, transposed-S, no online max, ASYNC K/V staging (R8
// structure) + ones-MFMA denominator (R11). LDS layouts (R4-verified):
//   Ks[key*8 + oct^swk(key)], swk(key) = (key&3)|(((key>>3)&1)<<2)
//   Vs[hd*8  + oct^(hd&7)]
// R12: 1D grid + XCD-locality swizzle. Decode:
//   xcd = L&7, ix = L>>3, bh = xcd*8 + (ix>>4), qb = ix&15.
// -> all 16 q-blocks of one (b,h) on one XCD; its K/V (512KB) L2-resident
// (verified: FETCH 140MB -> 25.6MB).
// ---------------------------------------------------------------------------
__global__ __launch_bounds__(256, 4) void attn(
    const bf16* __restrict__ Qb, const bf16* __restrict__ Kb,
    const bf16* __restrict__ Vt, bf16* __restrict__ Ob)
{
  constexpr int S = 2048, D = 1024;
  __shared__ alignas(16) bf16 Ks[2][4096];
  __shared__ alignas(16) bf16 Vs[2][4096];

  const int tid  = threadIdx.x;
  const int lane = tid & 63;
  const int wv   = tid >> 6;
  const int l15  = lane & 15;
  const int q0   = lane >> 4;

  // XCD-locality decode (bijective on [0,1024))
  const int L   = blockIdx.x;
  const int xcd = L & 7;
  const int ix  = L >> 3;
  const int bh  = xcd * 8 + (ix >> 4);
  const int qb  = ix & 15;
  const int b = bh >> 4, h = bh & 15;
  const int qblk = qb * 128 + wv * 32;

  bf16x8 qf[2][2];
  #pragma unroll
  for (int qt = 0; qt < 2; ++qt)
    #pragma unroll
    for (int dh = 0; dh < 2; ++dh)
      qf[qt][dh] = *(const bf16x8*)(
          Qb + (size_t)(b * S + qblk + qt * 16 + l15) * D + h * 64 + dh * 32 + q0 * 8);

  // all-ones A-fragment for the denominator MFMA
  bf16x8 ones;
  #pragma unroll
  for (int i = 0; i < 8; ++i) ones[i] = (bf16)1.0f;

  f32x4 lacc[2];       // lacc[qt][r]: every element = sum_k P[q,k]
  lacc[0] = (f32x4){0.f, 0.f, 0.f, 0.f};
  lacc[1] = (f32x4){0.f, 0.f, 0.f, 0.f};

  f32x4 o[4][2];   // o[ht][qt]
  #pragma unroll
  for (int ht = 0; ht < 4; ++ht)
    #pragma unroll
    for (int qt = 0; qt < 2; ++qt)
      o[ht][qt] = (f32x4){0.f, 0.f, 0.f, 0.f};

  // async staging: wave wv covers rows 16wv..16wv+15 (keys for K, hd for V)
  const int r8a = lane >> 3;                    // 0..7
  const int oc1 = (lane & 7) ^ (r8a & 3);       // K rows 16wv..+7   (bit3=0)
  const int oc2 = oc1 ^ 4;                      // K rows 16wv+8..+15 (bit3=1)
  const int ov  = (lane & 7) ^ r8a;             // V (hd&7 == r8a both halves)
  const bf16* kgw = Kb + (size_t)(b * S) * D + h * 64 + (size_t)(16 * wv) * D;
  const bf16* vgw = Vt + (size_t)(b * 16 + h) * (2048 * 64) + (16 * wv) * 64;

#define STAGE(KC, BUF)                                                        \
  {                                                                           \
    const bf16* ks = kgw + (size_t)(KC) * D;                                  \
    ASYNC_CP16(&Ks[BUF][wv * 1024],       ks + (size_t)r8a * D + oc1 * 8);    \
    ASYNC_CP16(&Ks[BUF][wv * 1024 + 512], ks + (size_t)(8 + r8a) * D + oc2 * 8);\
    const bf16* vs = vgw + (KC) * 64;                                         \
    ASYNC_CP16(&Vs[BUF][wv * 1024],       vs + r8a * 64 + ov * 8);            \
    ASYNC_CP16(&Vs[BUF][wv * 1024 + 512], vs + (8 + r8a) * 64 + ov * 8);      \
  }

  const int kla = 8 * (l15 >> 2) + (l15 & 3);            // permuted key base
  const int swa = (l15 & 3) | (((l15 >> 2) & 1) << 2);   // K-read swizzle
  const int swv = l15 & 7;                               // V-read swizzle

  STAGE(0, 0);

  for (int kc = 0, it = 0; kc < S; kc += 64, ++it) {
    const int cur = it & 1;
    __syncthreads();
    if (kc + 64 < S) STAGE(kc + 64, cur ^ 1);

    __builtin_amdgcn_s_setprio(1);

    f32x4 sc[2][4];
    #pragma unroll
    for (int kt = 0; kt < 4; ++kt) {
      const int key = kla + 4 * (kt & 1) + 32 * (kt >> 1);
      const bf16x8 kf0 = *(const bf16x8*)(&Ks[cur][(key * 8 + (q0 ^ swa)) * 8]);
      const bf16x8 kf1 = *(const bf16x8*)(&Ks[cur][(key * 8 + ((q0 + 4) ^ swa)) * 8]);
      #pragma unroll
      for (int qt = 0; qt < 2; ++qt) {
        f32x4 s = MFMA_BF16(kf0, qf[qt][0], ((f32x4){0.f, 0.f, 0.f, 0.f}));
        sc[qt][kt] = MFMA_BF16(kf1, qf[qt][1], s);
      }
    }

    bf16x8 pb[2][2];
    #pragma unroll
    for (int qt = 0; qt < 2; ++qt) {
      #pragma unroll
      for (int kt = 0; kt < 4; ++kt)
        #pragma unroll
        for (int r = 0; r < 4; ++r)
          pb[qt][kt >> 1][(kt & 1) * 4 + r] = (bf16)EXP2F(sc[qt][kt][r]);
    }

    // denominator on the matrix pipe: lacc[qt] += ones x pb[qt][half]
    #pragma unroll
    for (int qt = 0; qt < 2; ++qt) {
      lacc[qt] = MFMA_BF16(ones, pb[qt][0], lacc[qt]);
      lacc[qt] = MFMA_BF16(ones, pb[qt][1], lacc[qt]);
    }

    #pragma unroll
    for (int ht = 0; ht < 4; ++ht) {
      const int row = ht * 16 + l15;
      const bf16x8 vf0 = *(const bf16x8*)(&Vs[cur][(row * 8 + (q0 ^ swv)) * 8]);
      const bf16x8 vf1 = *(const bf16x8*)(&Vs[cur][(row * 8 + ((q0 + 4) ^ swv)) * 8]);
      #pragma unroll
      for (int qt = 0; qt < 2; ++qt) {
        o[ht][qt] = MFMA_BF16(vf0, pb[qt][0], o[ht][qt]);
        o[ht][qt] = MFMA_BF16(vf1, pb[qt][1], o[ht][qt]);
      }
    }

    __builtin_amdgcn_s_setprio(0);
  }
#undef STAGE

  #pragma unroll
  for (int qt = 0; qt < 2; ++qt) {
    const float inv = 1.0f / lacc[qt][0];   // every lane holds full l for its q=l15
    bf16* orow = Ob + (size_t)(b * S + qblk + qt * 16 + l15) * D + h * 64 + q0 * 4;
    #pragma unroll
    for (int ht = 0; ht < 4; ++ht) {
      bf16x4 w;
      w[0] = (bf16)(o[ht][qt][0] * inv);
      w[1] = (bf16)(o[ht][qt][1] * inv);
      w[2] = (bf16)(o[ht][qt][2] * inv);
      w[3] = (bf16)(o[ht][qt][3] * inv);
      *(bf16x4*)(orow + ht * 16) = w;
    }
  }
}

// ---------------------------------------------------------------------------
extern "C" void kernel_launch(void* const* d_in, const int* in_sizes, int n_in,
                              void* d_out, int out_size, void* d_ws, size_t ws_size,
                              hipStream_t stream)
{
  const float* x  = (const float*)d_in[0];
  const float* Wq = (const float*)d_in[1];
  const float* bq = (const float*)d_in[2];
  const float* Wk = (const float*)d_in[3];
  const float* bk = (const float*)d_in[4];
  const float* Wv = (const float*)d_in[5];
  const float* bv = (const float*)d_in[6];
  const float* Wo = (const float*)d_in[7];
  const float* bo = (const float*)d_in[8];
  float* out = (float*)d_out;

  const size_t NX = (size_t)8192 * 1024;
  const size_t NW = (size_t)1024 * 1024;

  bf16* xb  = (bf16*)d_ws;
  bf16* Wqb = xb  + NX;
  bf16* Wkb = Wqb + NW;
  bf16* Wvb = Wkb + NW;
  bf16* Wob = Wvb + NW;
  bf16* Qb  = Wob + NW;
  bf16* Kb  = Qb  + NX;
  bf16* Vt  = Kb  + NX;   // chunk-major [BH][S/64][HD][64]
  bf16* Ctx = Vt  + NX;

  const float QSCALE = 0.18033688011112042f;  // 0.125 * log2(e)

  dim3 bc(256, 1, 1);
  hipLaunchKernelGGL(cvt5, dim3(1024, 5, 1), bc, 0, stream,
                     x, xb, (int)NX, Wq, Wqb, (int)NW, Wk, Wkb, (int)NW,
                     Wv, Wvb, (int)NW, Wo, Wob, (int)NW);

  hipLaunchKernelGGL(gemm_qkv, dim3(24, 64, 1), bc, 0, stream,
                     xb, Wqb, Wkb, Wvb, bq, bk, bv, Qb, Kb, Vt, QSCALE);

  hipLaunchKernelGGL(attn, dim3(1024, 1, 1), bc, 0, stream, Qb, Kb, Vt, Ctx);

  hipLaunchKernelGGL(gemm_o, dim3(512, 1, 1), bc, 0, stream, Ctx, Wob, bo, out);
}